// Round 5
// baseline (341.146 us; speedup 1.0000x reference)
//
#include <hip/hip_runtime.h>

// ---------------------------------------------------------------------------
// AttentionBlock: GroupNorm(32) -> q,k,v = xn@W+b -> softmax(q k^T / sqrt(C)) v
//                 -> out@wp+bp + x.   B=2, H=W=64, C=512, S=4096 per batch.
// Round 16: r12 champion (156us fattn) + V-IN-REGISTERS (minimal delta).
//   r13/r15 post-mortem: every phase-structure rewrite regressed; r12's
//   2-barrier everyone-does-both structure stands. Re-audit shows the LDS
//   port also pays the staging WRITE side (64KB/chunk, 1:4 load:MFMA vs
//   m97's 1:8): V is a pure LDS round-trip with zero reuse (each V frag
//   feeds exactly one PV read). Fix: prefetch V frags into 16 VGPRs at
//   chunk-top (full S-phase of latency cover -- r14's failure was direct
//   per-fragment MFMA feeds with no prefetch distance, for BOTH operands).
//   K keeps its 4x-reuse LDS path, byte-identical to r12.
//   + S accumulation split into 2 chains (16-deep -> 8-deep),
//   + T5 setprio(1) around S/PV MFMA clusters (m191 attn-positive).
//   LDS 139264 -> 69632 B.
// Keeps r9/r11 verified structure for gn/xn/QKV/OUT and r12 combine2.
// ---------------------------------------------------------------------------

typedef __bf16 bf16_t;
typedef __bf16 bf16x8 __attribute__((ext_vector_type(8)));
typedef __bf16 bf16x4 __attribute__((ext_vector_type(4)));
typedef float  f32x4  __attribute__((ext_vector_type(4)));

__device__ __forceinline__ bf16x8 ld8(const bf16_t* p) {
    return *reinterpret_cast<const bf16x8*>(p);
}
__device__ __forceinline__ f32x4 mfma16(bf16x8 a, bf16x8 b, f32x4 c) {
    return __builtin_amdgcn_mfma_f32_16x16x32_bf16(a, b, c, 0, 0, 0);
}
__device__ __forceinline__ void gload16(const bf16_t* gp, bf16_t* lp) {
    // HW semantics: LDS dest = wave-uniform base + laneid*16B; gp per-lane.
    __builtin_amdgcn_global_load_lds(
        (const __attribute__((address_space(1))) void*)gp,
        (__attribute__((address_space(3))) void*)lp, 16, 0, 0);
}

#define NPIX 8192      // B*H*W
#define C512 512
#define SEQ  4096      // H*W per batch
#define QSCALE 0.044194173824159216f   // 512^-0.5

// ---------------- GroupNorm partial sums: 512 blocks (8 slices x 64 bg) -----
__global__ __launch_bounds__(256) void gn_sum_k(const float* __restrict__ x,
                                                float* __restrict__ accum) {
    int bg    = blockIdx.x >> 3;        // 0..63 = b*32+g
    int slice = blockIdx.x & 7;         // 512-pixel slice
    int b = bg >> 5, g = bg & 31;
    const float* xp = x + (size_t)b * SEQ * C512 + g * 16;
    float s = 0.f, s2 = 0.f;
    #pragma unroll
    for (int pp = 0; pp < 2; pp++) {
        int p = slice * 512 + pp * 256 + threadIdx.x;
        const float4* q = reinterpret_cast<const float4*>(xp + (size_t)p * C512);
        #pragma unroll
        for (int i = 0; i < 4; i++) {
            float4 v = q[i];
            s  += v.x + v.y + v.z + v.w;
            s2 += v.x*v.x + v.y*v.y + v.z*v.z + v.w*v.w;
        }
    }
    #pragma unroll
    for (int off = 32; off >= 1; off >>= 1) {
        s  += __shfl_down(s, off);
        s2 += __shfl_down(s2, off);
    }
    __shared__ float rs[4], rs2[4];
    int wave = threadIdx.x >> 6;
    if ((threadIdx.x & 63) == 0) { rs[wave] = s; rs2[wave] = s2; }
    __syncthreads();
    if (threadIdx.x == 0) {
        float S = rs[0] + rs[1] + rs[2] + rs[3];
        float S2 = rs2[0] + rs2[1] + rs2[2] + rs2[3];
        atomicAdd(&accum[bg * 2],     S);
        atomicAdd(&accum[bg * 2 + 1], S2);
    }
}

// ---------------- weights: fp32 (k,n) -> bf16 transposed (n,k) --------------
__global__ __launch_bounds__(256) void wt_conv_k(const float* wq, const float* wk,
                                                 const float* wv, const float* wp,
                                                 bf16_t* wqkvT, bf16_t* wpT) {
    int y = blockIdx.y;
    const float* w = (y == 0) ? wq : (y == 1) ? wk : (y == 2) ? wv : wp;
    float scale = (y == 0) ? QSCALE : 1.0f;
    int tid = blockIdx.x * 256 + threadIdx.x;     // 262144 total
    int n = tid >> 9, k = tid & 511;
    bf16_t val = (bf16_t)(w[(size_t)k * C512 + n] * scale);
    if (y < 3) wqkvT[((size_t)y * C512 + n) * C512 + k] = val;
    else       wpT[(size_t)n * C512 + k] = val;
}

// ---------------- merged qkv bias (Q segment pre-scaled) --------------------
__global__ __launch_bounds__(256) void bias_merge_k(const float* bq, const float* bk,
                                                    const float* bv, float* bqkv) {
    int i = blockIdx.x * 256 + threadIdx.x;       // 1536
    float v = (i < 512) ? bq[i] * QSCALE : (i < 1024) ? bk[i - 512] : bv[i - 1024];
    bqkv[i] = v;
}

// ---------------- xn = groupnorm(x)*gamma+beta -> bf16 ----------------------
__global__ __launch_bounds__(256) void xn_k(const float* __restrict__ x,
                                            const float* __restrict__ accum,
                                            const float* __restrict__ gamma,
                                            const float* __restrict__ beta,
                                            bf16_t* __restrict__ xn) {
    size_t idx = ((size_t)blockIdx.x * 256 + threadIdx.x) * 4;   // elem index
    int c = (int)(idx & 511);
    size_t pix = idx >> 9;
    int b = (int)(pix >> 12);
    int g = c >> 4;
    float sum = accum[(b * 32 + g) * 2];
    float ssq = accum[(b * 32 + g) * 2 + 1];
    float mean = sum * (1.f / 65536.f);
    float var  = ssq * (1.f / 65536.f) - mean * mean;
    float rstd = rsqrtf(var + 1e-5f);
    float4 v  = *reinterpret_cast<const float4*>(x + idx);
    float4 gm = *reinterpret_cast<const float4*>(gamma + c);
    float4 bt = *reinterpret_cast<const float4*>(beta + c);
    bf16x4 o;
    o[0] = (bf16_t)((v.x - mean) * rstd * gm.x + bt.x);
    o[1] = (bf16_t)((v.y - mean) * rstd * gm.y + bt.y);
    o[2] = (bf16_t)((v.z - mean) * rstd * gm.z + bt.z);
    o[3] = (bf16_t)((v.w - mean) * rstd * gm.w + bt.w);
    *reinterpret_cast<bf16x4*>(xn + idx) = o;
}

// ---------------- unified TMx128-tile GEMM (m97 structure) ------------------
// MODE 0: QKV (TM=128) — A=xn, B=wqkvT(1536x512). Epilogue: +bqkv; cols
//                0-511 -> Q, 512-1023 -> K (row-major), 1024-1535 -> VT.
// MODE 3: OUT (TM=64)  — A=O, B=wpT. Epilogue: +bp +resid, fp32 out.
template <int MODE>
__global__ __launch_bounds__(256, 2) void gemm128_k(
        const bf16_t* __restrict__ Aall, const bf16_t* __restrict__ Ball,
        const float* __restrict__ bias, const float* __restrict__ resid,
        void* __restrict__ out0, void* __restrict__ out1,
        void* __restrict__ out2, void* __restrict__ out3,
        float* __restrict__ lsum) {
    constexpr int TM  = (MODE == 3) ? 64 : 128;
    constexpr int ASZ = TM * 32;          // A elems per buffer
    constexpr int ACH = TM / 16;          // A chunks per step
    constexpr int CPW = (ACH + 8) / 4;    // staging chunks per wave
    constexpr int MI  = TM / 32;          // m-tiles per wave
    __shared__ bf16_t smem[2 * ASZ + 8192];   // A dbuf + B dbuf

    int lane = threadIdx.x & 63;
    int w    = threadIdx.x >> 6;          // 4 waves, 2x2
    int wr   = w >> 1, wc = w & 1;
    int lrow = lane & 15, quad = lane >> 4;

    const bf16_t* A = Aall;
    const bf16_t* B = Ball;
    size_t lda = 512, ldb = 512;
    int ksteps = 16;

    int bm = blockIdx.x * TM, bn = blockIdx.y * 128;

    // stage K-step ks into buffer buf: ACH A-chunks + 8 B-chunks
    auto stage = [&](int buf, int ks) {
        size_t k0 = (size_t)ks * 32;
        #pragma unroll
        for (int ii = 0; ii < CPW; ii++) {
            int c = w * CPW + ii;
            if (c < ACH) {
                const bf16_t* gpA = A + (size_t)(bm + c * 16 + lrow) * lda + k0 + quad * 8;
                gload16(gpA, &smem[buf * ASZ + c * 512]);
            } else {
                int cb = c - ACH;
                const bf16_t* gpB = B + (size_t)(bn + cb * 16 + lrow) * ldb + k0 + quad * 8;
                gload16(gpB, &smem[2 * ASZ + buf * 4096 + cb * 512]);
            }
        }
    };

    f32x4 acc[MI][4] = {};

    stage(0, 0);

    for (int ks = 0; ks < ksteps; ks++) {
        int cur = ks & 1;
        __syncthreads();                 // drains stage(ks); WAR for dbuf
        if (ks + 1 < ksteps) stage(1 - cur, ks + 1);

        const bf16_t* al = &smem[cur * ASZ + (wr * MI) * 512];
        const bf16_t* bl = &smem[2 * ASZ + cur * 4096 + (wc * 4) * 512];
        bf16x8 af[MI], bf[4];
        #pragma unroll
        for (int m = 0; m < MI; m++) af[m] = ld8(al + m * 512 + lane * 8);
        #pragma unroll
        for (int n = 0; n < 4; n++) bf[n] = ld8(bl + n * 512 + lane * 8);
        #pragma unroll
        for (int m = 0; m < MI; m++)
            #pragma unroll
            for (int n = 0; n < 4; n++)
                acc[m][n] = mfma16(af[m], bf[n], acc[m][n]);
    }

    // ---- epilogue; C/D layout: col=lane&15, row=quad*4+reg ----
    #pragma unroll
    for (int m = 0; m < MI; m++) {
        int rowb = bm + wr * (TM / 2) + m * 16 + quad * 4;
        #pragma unroll
        for (int n = 0; n < 4; n++) {
            int col = bn + wc * 64 + n * 16 + lrow;
            #pragma unroll
            for (int i = 0; i < 4; i++) {
                int row = rowb + i;
                float v = acc[m][n][i];
                if (MODE == 0) {
                    int seg = col >> 9, c = col & 511;
                    bf16_t val = (bf16_t)(v + bias[col]);
                    if (seg == 0) {
                        ((bf16_t*)out0)[(size_t)row * C512 + c] = val;
                    } else if (seg == 1) {
                        ((bf16_t*)out1)[(size_t)row * C512 + c] = val;
                    } else {
                        int b = row >> 12, s = row & 4095;
                        ((bf16_t*)out2)[((size_t)(b * C512 + c)) * SEQ + s] = val;
                    }
                } else {
                    size_t idx = (size_t)row * C512 + col;
                    ((float*)out0)[idx] = v + bias[col] + resid[idx];
                }
            }
        }
    }
}

// ---------------- fused attention: O_partial = exp(Q K^T) V, lsum ----------
// 256 blocks x 512 thr (8 waves). Block = (batch, kv-half of 2048 keys,
// 64 q-rows), XCD-swizzled so each XCD streams one (b,kv) K/V-half (4MB=L2).
// r12 structure: per 32-key chunk, S = Q.K^T (Q-frags in regs, K from dbuf
// LDS), P=exp(min(s,20)) through a 4KB LDS buffer, O += P.V.  DELTA vs r12:
// V comes straight from L2 into 16 VGPRs, prefetched at chunk-top (a full
// S-phase of latency cover); no Vl in LDS. K staging via global_load_lds,
// double-buffered; mid-chunk barrier is raw s_barrier + lgkmcnt(0) so K
// staging stays in flight across it. S split into 2 MFMA chains; setprio(1)
// around both MFMA clusters.
__global__ __launch_bounds__(512, 1) void fattn_k(
        const bf16_t* __restrict__ Q, const bf16_t* __restrict__ K,
        const bf16_t* __restrict__ VT, bf16_t* __restrict__ Op0,
        bf16_t* __restrict__ Op1, float* __restrict__ lsum) {
    __shared__ bf16_t Kl[2][32 * 512];   // [buf][32 keys x 512 k] frag-major
    __shared__ bf16_t Pl[64 * 32];       // P chunk, A-frag-major (4 chunks)

    int bid = blockIdx.x;
    int xcd = bid & 7, loc = bid >> 3;    // 8 XCDs x 32 blocks
    int b   = (xcd >> 1) & 1;
    int kv  = xcd & 1;
    int q0  = ((xcd >> 2) * 32 + loc) * 64;
    int key0 = kv * 2048;

    const bf16_t* Qb = Q  + (size_t)b * SEQ * C512;
    const bf16_t* Kb = K  + (size_t)b * SEQ * C512;
    const bf16_t* Vb = VT + (size_t)b * C512 * SEQ;
    bf16_t* Op = kv ? Op1 : Op0;

    int lane = threadIdx.x & 63;
    int w    = threadIdx.x >> 6;          // 8 waves
    int lrow = lane & 15, quad = lane >> 4;
    int qt = w & 3, kt = w >> 2;          // S-phase: q-tile, key-tile-of-2

    // Q fragments: this wave's 16 q-rows x full K=512 (64 VGPR)
    bf16x8 qf[16];
    const bf16_t* qp = Qb + (size_t)(q0 + qt * 16 + lrow) * C512 + quad * 8;
    #pragma unroll
    for (int ks = 0; ks < 16; ks++) qf[ks] = ld8(qp + ks * 32);

    // K staging: 32 chunks x 512 elems; wave w stages [4w, 4w+4)
    auto stageK = [&](int buf, int t) {
        #pragma unroll
        for (int ii = 0; ii < 4; ii++) {
            int cc = w * 4 + ii;
            int ks = cc >> 1, ktc = cc & 1;
            const bf16_t* gp = Kb +
                (size_t)(key0 + t * 32 + ktc * 16 + lrow) * C512 + ks * 32 + quad * 8;
            gload16(gp, &Kl[buf][cc * 512]);
        }
    };
    // V fragment base: this wave's 64-col slice, row c = w*64 + n*16 + lrow
    const bf16_t* vbase = Vb + (size_t)(w * 64 + lrow) * SEQ + key0 + quad * 8;

    f32x4 oacc[4][4] = {};                // rows m*16+quad*4+i, cols w*64+n*16+lrow
    float rs[4] = {0.f, 0.f, 0.f, 0.f};

    stageK(0, 0);

    for (int t = 0; t < 64; t++) {
        int cur = t & 1;
        __syncthreads();                  // stageK(t) landed; dbuf + Pl WAR
        if (t < 63) stageK(1 - cur, t + 1);

        // ---- V(t) register prefetch (consumed after mid-barrier) ----
        bf16x8 vf[4];
        const bf16_t* vp = vbase + (size_t)t * 32;
        #pragma unroll
        for (int n = 0; n < 4; n++) vf[n] = ld8(vp + (size_t)(n * 16) * SEQ);

        // ---- S: sa = Q[qt-tile] . K[kt-tile]^T over K=512, 2 chains ----
        f32x4 sa0 = {}, sa1 = {};
        __builtin_amdgcn_s_setprio(1);
        #pragma unroll
        for (int ks = 0; ks < 8; ks++) {
            bf16x8 kf0 = ld8(&Kl[cur][((2 * ks) * 2 + kt) * 512 + lane * 8]);
            bf16x8 kf1 = ld8(&Kl[cur][((2 * ks + 1) * 2 + kt) * 512 + lane * 8]);
            sa0 = mfma16(qf[2 * ks],     kf0, sa0);
            sa1 = mfma16(qf[2 * ks + 1], kf1, sa1);
        }
        __builtin_amdgcn_s_setprio(0);
        f32x4 sa = sa0 + sa1;
        // ---- exp -> P (LDS, A-frag-major), accumulate row-sum partials ----
        #pragma unroll
        for (int i = 0; i < 4; i++) {
            float p = __expf(fminf(sa[i], 20.0f));
            rs[i] += p;
            // P[row=quad*4+i][key=kt*16+lrow] of chunk qt, lane-linear layout
            int off = qt * 512 + (quad * 4 + i) * 8 +
                      (kt * 2 + (lrow >> 3)) * 128 + (lrow & 7);
            Pl[off] = (bf16_t)p;
        }
        asm volatile("s_waitcnt lgkmcnt(0)" ::: "memory");
        __builtin_amdgcn_s_barrier();     // P visible; K staging stays in flight
        __builtin_amdgcn_sched_barrier(0);

        // ---- PV: oacc[m][n] += P[m-tile] . V-regs (s-chunk=32) ----
        bf16x8 pa[4];
        #pragma unroll
        for (int m = 0; m < 4; m++) pa[m] = ld8(&Pl[m * 512 + lane * 8]);
        __builtin_amdgcn_s_setprio(1);
        #pragma unroll
        for (int n = 0; n < 4; n++)
            #pragma unroll
            for (int m = 0; m < 4; m++)
                oacc[m][n] = mfma16(pa[m], vf[n], oacc[m][n]);
        __builtin_amdgcn_s_setprio(0);
    }

    // ---- row-sums: reduce over 16 col-lanes, one atomicAdd per row ----
    #pragma unroll
    for (int i = 0; i < 4; i++) {
        float r = rs[i];
        r += __shfl_xor(r, 1);
        r += __shfl_xor(r, 2);
        r += __shfl_xor(r, 4);
        r += __shfl_xor(r, 8);
        if (lrow == 0)
            atomicAdd(&lsum[(size_t)b * SEQ + q0 + qt * 16 + quad * 4 + i], r);
    }

    // ---- write unnormalized partial O (64 x 512 per block) ----
    #pragma unroll
    for (int m = 0; m < 4; m++) {
        int row = q0 + m * 16 + quad * 4;
        #pragma unroll
        for (int n = 0; n < 4; n++) {
            int col = w * 64 + n * 16 + lrow;
            #pragma unroll
            for (int i = 0; i < 4; i++)
                Op[((size_t)b * SEQ + row + i) * C512 + col] = (bf16_t)oacc[m][n][i];
        }
    }
}

// ---------------- combine 2 kv-half partials: O = (Op0+Op1)/lsum ------------
__global__ __launch_bounds__(256) void attn_combine2_k(
        const bf16_t* __restrict__ Op0, const bf16_t* __restrict__ Op1,
        const float* __restrict__ lsum, bf16_t* __restrict__ O) {
    int idx = blockIdx.x * 256 + threadIdx.x;    // 524288 threads
    int row = idx >> 6;                          // global row 0..8191
    int c8  = (idx & 63) << 3;
    float inv = 1.0f / lsum[row];
    size_t base = (size_t)row * C512 + c8;
    bf16x8 o0 = ld8(Op0 + base), o1 = ld8(Op1 + base);
    bf16x8 o;
    #pragma unroll
    for (int j = 0; j < 8; j++)
        o[j] = (bf16_t)(((float)o0[j] + (float)o1[j]) * inv);
    *reinterpret_cast<bf16x8*>(O + base) = o;
}

// ---------------------------------------------------------------------------
extern "C" void kernel_launch(void* const* d_in, const int* in_sizes, int n_in,
                              void* d_out, int out_size, void* d_ws, size_t ws_size,
                              hipStream_t stream) {
    const float* x     = (const float*)d_in[0];
    const float* gamma = (const float*)d_in[1];
    const float* beta  = (const float*)d_in[2];
    const float* wq = (const float*)d_in[3];  const float* bq = (const float*)d_in[4];
    const float* wk = (const float*)d_in[5];  const float* bk = (const float*)d_in[6];
    const float* wv = (const float*)d_in[7];  const float* bv = (const float*)d_in[8];
    const float* wp = (const float*)d_in[9];  const float* bp = (const float*)d_in[10];
    float* out = (float*)d_out;

    char* ws = (char*)d_ws;
    size_t off = 0;
    float*  bqkv   = (float*)(ws + off);   off += 1536 * sizeof(float);
    float*  lsum   = (float*)(ws + off);   off += (size_t)NPIX * sizeof(float);
    float*  accum  = (float*)(ws + off);   off += 128 * sizeof(float);
    bf16_t* xn     = (bf16_t*)(ws + off);  off += (size_t)NPIX * C512 * 2;  // later Ob
    bf16_t* wqkvT  = (bf16_t*)(ws + off);  off += (size_t)3 * C512 * C512 * 2;
    bf16_t* wpT    = (bf16_t*)(ws + off);  off += (size_t)C512 * C512 * 2;
    bf16_t* Qb     = (bf16_t*)(ws + off);  off += (size_t)NPIX * C512 * 2;
    bf16_t* Kb     = (bf16_t*)(ws + off);  off += (size_t)NPIX * C512 * 2;
    bf16_t* VTb    = (bf16_t*)(ws + off);  off += (size_t)NPIX * C512 * 2;
    bf16_t* Op0    = (bf16_t*)(ws + off);  off += (size_t)NPIX * C512 * 2;
    bf16_t* Op1    = (bf16_t*)(ws + off);  off += (size_t)NPIX * C512 * 2;
    bf16_t* Ob  = xn;    // xn dead after QKV GEMM

    // zero lsum + accum (contiguous)
    hipMemsetAsync(lsum, 0, (size_t)(NPIX + 128) * sizeof(float), stream);

    gn_sum_k<<<512, 256, 0, stream>>>(x, accum);
    wt_conv_k<<<dim3(1024, 4), 256, 0, stream>>>(wq, wk, wv, wp, wqkvT, wpT);
    bias_merge_k<<<6, 256, 0, stream>>>(bq, bk, bv, bqkv);
    xn_k<<<4096, 256, 0, stream>>>(x, accum, gamma, beta, xn);

    // QKV: (8192 x 1536) = xn @ wqkvT^T
    gemm128_k<0><<<dim3(64, 12, 1), 256, 0, stream>>>(
        xn, wqkvT, bqkv, nullptr, Qb, Kb, VTb, nullptr, nullptr);

    // fused attention: per-(batch, kv-half) unnormalized O partials + lsum
    fattn_k<<<256, 512, 0, stream>>>(Qb, Kb, VTb, Op0, Op1, lsum);

    // combine: O = (Op0+Op1)/lsum
    attn_combine2_k<<<2048, 256, 0, stream>>>(Op0, Op1, lsum, Ob);

    // OUT: (8192 x 512) = O @ wpT^T + bp + x, 64-row tiles -> 512 blocks
    gemm128_k<3><<<dim3(128, 4, 1), 256, 0, stream>>>(
        Ob, wpT, bp, x, out, nullptr, nullptr, nullptr, nullptr);
}

// Round 6
// 304.528 us; speedup vs baseline: 1.1202x; 1.1202x over previous
//
#include <hip/hip_runtime.h>

// ---------------------------------------------------------------------------
// AttentionBlock: GroupNorm(32) -> q,k,v = xn@W+b -> softmax(q k^T / sqrt(C)) v
//                 -> out@wp+bp + x.   B=2, H=W=64, C=512, S=4096 per batch.
// Round 17: r12 champion fattn + intra-wave tweaks only; pipeline fusion.
//   Law from r13-r16: r12's 2-barrier stage-at-top all-LDS structure is
//   self-consistent. Register global loads consumed in-chunk force an
//   effective vmcnt(0) that drains K-staging (r14/r16 regressions); barrier
//   restructures break wave interleave (r13/r15). So fattn here is r12
//   BYTE-IDENTICAL except: (a) setprio(1) around S and PV MFMA clusters
//   (T5, m191 attn-positive, untested on r12), (b) S accum split into two
//   8-deep chains (was one 16-deep dependent MFMA chain).
//   Pipeline: combine2 deleted -- lsum normalization commutes with the wp
//   matmul (per-row scalar), so OUT GEMM runs 32 k-steps (16 over Op0 + 16
//   over Op1 into one accumulator) and scales by 1/lsum[row] in epilogue.
//   bias_merge folded into wt_conv (y==4). Two fewer dispatches, -17MB HBM.
// Keeps r9/r11 verified structure for gn/xn/QKV.
// ---------------------------------------------------------------------------

typedef __bf16 bf16_t;
typedef __bf16 bf16x8 __attribute__((ext_vector_type(8)));
typedef __bf16 bf16x4 __attribute__((ext_vector_type(4)));
typedef float  f32x4  __attribute__((ext_vector_type(4)));

__device__ __forceinline__ bf16x8 ld8(const bf16_t* p) {
    return *reinterpret_cast<const bf16x8*>(p);
}
__device__ __forceinline__ f32x4 mfma16(bf16x8 a, bf16x8 b, f32x4 c) {
    return __builtin_amdgcn_mfma_f32_16x16x32_bf16(a, b, c, 0, 0, 0);
}
__device__ __forceinline__ void gload16(const bf16_t* gp, bf16_t* lp) {
    // HW semantics: LDS dest = wave-uniform base + laneid*16B; gp per-lane.
    __builtin_amdgcn_global_load_lds(
        (const __attribute__((address_space(1))) void*)gp,
        (__attribute__((address_space(3))) void*)lp, 16, 0, 0);
}

#define NPIX 8192      // B*H*W
#define C512 512
#define SEQ  4096      // H*W per batch
#define QSCALE 0.044194173824159216f   // 512^-0.5

// ---------------- GroupNorm partial sums: 512 blocks (8 slices x 64 bg) -----
__global__ __launch_bounds__(256) void gn_sum_k(const float* __restrict__ x,
                                                float* __restrict__ accum) {
    int bg    = blockIdx.x >> 3;        // 0..63 = b*32+g
    int slice = blockIdx.x & 7;         // 512-pixel slice
    int b = bg >> 5, g = bg & 31;
    const float* xp = x + (size_t)b * SEQ * C512 + g * 16;
    float s = 0.f, s2 = 0.f;
    #pragma unroll
    for (int pp = 0; pp < 2; pp++) {
        int p = slice * 512 + pp * 256 + threadIdx.x;
        const float4* q = reinterpret_cast<const float4*>(xp + (size_t)p * C512);
        #pragma unroll
        for (int i = 0; i < 4; i++) {
            float4 v = q[i];
            s  += v.x + v.y + v.z + v.w;
            s2 += v.x*v.x + v.y*v.y + v.z*v.z + v.w*v.w;
        }
    }
    #pragma unroll
    for (int off = 32; off >= 1; off >>= 1) {
        s  += __shfl_down(s, off);
        s2 += __shfl_down(s2, off);
    }
    __shared__ float rs[4], rs2[4];
    int wave = threadIdx.x >> 6;
    if ((threadIdx.x & 63) == 0) { rs[wave] = s; rs2[wave] = s2; }
    __syncthreads();
    if (threadIdx.x == 0) {
        float S = rs[0] + rs[1] + rs[2] + rs[3];
        float S2 = rs2[0] + rs2[1] + rs2[2] + rs2[3];
        atomicAdd(&accum[bg * 2],     S);
        atomicAdd(&accum[bg * 2 + 1], S2);
    }
}

// ---------------- weights fp32 (k,n) -> bf16 (n,k); y==4: merged qkv bias ---
__global__ __launch_bounds__(256) void wt_conv_k(const float* wq, const float* wk,
                                                 const float* wv, const float* wp,
                                                 const float* bq, const float* bk,
                                                 const float* bv,
                                                 bf16_t* wqkvT, bf16_t* wpT,
                                                 float* bqkv) {
    int y = blockIdx.y;
    if (y == 4) {                         // merged qkv bias (Q pre-scaled)
        if (blockIdx.x >= 6) return;
        int i = blockIdx.x * 256 + threadIdx.x;       // 1536
        float v = (i < 512) ? bq[i] * QSCALE : (i < 1024) ? bk[i - 512] : bv[i - 1024];
        bqkv[i] = v;
        return;
    }
    const float* w = (y == 0) ? wq : (y == 1) ? wk : (y == 2) ? wv : wp;
    float scale = (y == 0) ? QSCALE : 1.0f;
    int tid = blockIdx.x * 256 + threadIdx.x;     // 262144 total
    int n = tid >> 9, k = tid & 511;
    bf16_t val = (bf16_t)(w[(size_t)k * C512 + n] * scale);
    if (y < 3) wqkvT[((size_t)y * C512 + n) * C512 + k] = val;
    else       wpT[(size_t)n * C512 + k] = val;
}

// ---------------- xn = groupnorm(x)*gamma+beta -> bf16 ----------------------
__global__ __launch_bounds__(256) void xn_k(const float* __restrict__ x,
                                            const float* __restrict__ accum,
                                            const float* __restrict__ gamma,
                                            const float* __restrict__ beta,
                                            bf16_t* __restrict__ xn) {
    size_t idx = ((size_t)blockIdx.x * 256 + threadIdx.x) * 4;   // elem index
    int c = (int)(idx & 511);
    size_t pix = idx >> 9;
    int b = (int)(pix >> 12);
    int g = c >> 4;
    float sum = accum[(b * 32 + g) * 2];
    float ssq = accum[(b * 32 + g) * 2 + 1];
    float mean = sum * (1.f / 65536.f);
    float var  = ssq * (1.f / 65536.f) - mean * mean;
    float rstd = rsqrtf(var + 1e-5f);
    float4 v  = *reinterpret_cast<const float4*>(x + idx);
    float4 gm = *reinterpret_cast<const float4*>(gamma + c);
    float4 bt = *reinterpret_cast<const float4*>(beta + c);
    bf16x4 o;
    o[0] = (bf16_t)((v.x - mean) * rstd * gm.x + bt.x);
    o[1] = (bf16_t)((v.y - mean) * rstd * gm.y + bt.y);
    o[2] = (bf16_t)((v.z - mean) * rstd * gm.z + bt.z);
    o[3] = (bf16_t)((v.w - mean) * rstd * gm.w + bt.w);
    *reinterpret_cast<bf16x4*>(xn + idx) = o;
}

// ---------------- unified TMx128-tile GEMM (m97 structure) ------------------
// MODE 0: QKV (TM=128) — A=xn, B=wqkvT(1536x512). Epilogue: +bqkv; cols
//                0-511 -> Q, 512-1023 -> K (row-major), 1024-1535 -> VT.
// MODE 3: OUT (TM=64)  — dual-A split-K: ksteps 0-15 over Op0, 16-31 over
//                Op1 (out1), same accumulator. Epilogue: acc/lsum[row]
//                + bp + resid, fp32 out.  (combine2 folded in: the per-row
//                lsum scalar commutes with the wp matmul.)
template <int MODE>
__global__ __launch_bounds__(256, 2) void gemm128_k(
        const bf16_t* __restrict__ Aall, const bf16_t* __restrict__ Ball,
        const float* __restrict__ bias, const float* __restrict__ resid,
        void* __restrict__ out0, void* __restrict__ out1,
        void* __restrict__ out2, void* __restrict__ out3,
        float* __restrict__ lsum) {
    constexpr int TM  = (MODE == 3) ? 64 : 128;
    constexpr int ASZ = TM * 32;          // A elems per buffer
    constexpr int ACH = TM / 16;          // A chunks per step
    constexpr int CPW = (ACH + 8) / 4;    // staging chunks per wave
    constexpr int MI  = TM / 32;          // m-tiles per wave
    __shared__ bf16_t smem[2 * ASZ + 8192];   // A dbuf + B dbuf

    int lane = threadIdx.x & 63;
    int w    = threadIdx.x >> 6;          // 4 waves, 2x2
    int wr   = w >> 1, wc = w & 1;
    int lrow = lane & 15, quad = lane >> 4;

    const bf16_t* A  = Aall;
    const bf16_t* A1 = (MODE == 3) ? (const bf16_t*)out1 : nullptr;
    const bf16_t* B  = Ball;
    size_t lda = 512, ldb = 512;
    int ksteps = (MODE == 3) ? 32 : 16;

    int bm = blockIdx.x * TM, bn = blockIdx.y * 128;

    // stage K-step ks into buffer buf: ACH A-chunks + 8 B-chunks
    auto stage = [&](int buf, int ks) {
        const bf16_t* Ap = (MODE == 3 && ks >= 16) ? A1 : A;
        size_t k0 = (size_t)(MODE == 3 ? (ks & 15) : ks) * 32;
        #pragma unroll
        for (int ii = 0; ii < CPW; ii++) {
            int c = w * CPW + ii;
            if (c < ACH) {
                const bf16_t* gpA = Ap + (size_t)(bm + c * 16 + lrow) * lda + k0 + quad * 8;
                gload16(gpA, &smem[buf * ASZ + c * 512]);
            } else {
                int cb = c - ACH;
                const bf16_t* gpB = B + (size_t)(bn + cb * 16 + lrow) * ldb + k0 + quad * 8;
                gload16(gpB, &smem[2 * ASZ + buf * 4096 + cb * 512]);
            }
        }
    };

    f32x4 acc[MI][4] = {};

    stage(0, 0);

    for (int ks = 0; ks < ksteps; ks++) {
        int cur = ks & 1;
        __syncthreads();                 // drains stage(ks); WAR for dbuf
        if (ks + 1 < ksteps) stage(1 - cur, ks + 1);

        const bf16_t* al = &smem[cur * ASZ + (wr * MI) * 512];
        const bf16_t* bl = &smem[2 * ASZ + cur * 4096 + (wc * 4) * 512];
        bf16x8 af[MI], bf[4];
        #pragma unroll
        for (int m = 0; m < MI; m++) af[m] = ld8(al + m * 512 + lane * 8);
        #pragma unroll
        for (int n = 0; n < 4; n++) bf[n] = ld8(bl + n * 512 + lane * 8);
        #pragma unroll
        for (int m = 0; m < MI; m++)
            #pragma unroll
            for (int n = 0; n < 4; n++)
                acc[m][n] = mfma16(af[m], bf[n], acc[m][n]);
    }

    // ---- epilogue; C/D layout: col=lane&15, row=quad*4+reg ----
    #pragma unroll
    for (int m = 0; m < MI; m++) {
        int rowb = bm + wr * (TM / 2) + m * 16 + quad * 4;
        #pragma unroll
        for (int n = 0; n < 4; n++) {
            int col = bn + wc * 64 + n * 16 + lrow;
            #pragma unroll
            for (int i = 0; i < 4; i++) {
                int row = rowb + i;
                float v = acc[m][n][i];
                if (MODE == 0) {
                    int seg = col >> 9, c = col & 511;
                    bf16_t val = (bf16_t)(v + bias[col]);
                    if (seg == 0) {
                        ((bf16_t*)out0)[(size_t)row * C512 + c] = val;
                    } else if (seg == 1) {
                        ((bf16_t*)out1)[(size_t)row * C512 + c] = val;
                    } else {
                        int b = row >> 12, s = row & 4095;
                        ((bf16_t*)out2)[((size_t)(b * C512 + c)) * SEQ + s] = val;
                    }
                } else {
                    size_t idx = (size_t)row * C512 + col;
                    float inv = 1.0f / lsum[row];
                    ((float*)out0)[idx] = v * inv + bias[col] + resid[idx];
                }
            }
        }
    }
}

// ---------------- fused attention: O_partial = exp(Q K^T) V, lsum ----------
// r12 champion structure, byte-identical except: setprio(1) around both MFMA
// clusters; S accumulation split into two 8-deep chains.
// 256 blocks x 512 thr (8 waves). Block = (batch, kv-half of 2048 keys,
// 64 q-rows), XCD-swizzled so each XCD streams one (b,kv) K/V-half (4MB=L2).
// Per 32-key chunk: S = Q.K^T (Q-frags in regs, K from dbuf LDS),
// P=exp(min(s,20)) through a 4KB LDS buffer, O += P.V (V from dbuf LDS).
// Mid-chunk barrier is raw s_barrier + lgkmcnt(0); staging stays in flight.
__global__ __launch_bounds__(512, 1) void fattn_k(
        const bf16_t* __restrict__ Q, const bf16_t* __restrict__ K,
        const bf16_t* __restrict__ VT, bf16_t* __restrict__ Op0,
        bf16_t* __restrict__ Op1, float* __restrict__ lsum) {
    __shared__ bf16_t Kl[2][32 * 512];   // [buf][32 keys x 512 k] frag-major
    __shared__ bf16_t Vl[2][512 * 32];   // [buf][512 c x 32 s]  frag-major
    __shared__ bf16_t Pl[64 * 32];       // P chunk, A-frag-major (4 chunks)

    int bid = blockIdx.x;
    int xcd = bid & 7, loc = bid >> 3;    // 8 XCDs x 32 blocks
    int b   = (xcd >> 1) & 1;
    int kv  = xcd & 1;
    int q0  = ((xcd >> 2) * 32 + loc) * 64;
    int key0 = kv * 2048;

    const bf16_t* Qb = Q  + (size_t)b * SEQ * C512;
    const bf16_t* Kb = K  + (size_t)b * SEQ * C512;
    const bf16_t* Vb = VT + (size_t)b * C512 * SEQ;
    bf16_t* Op = kv ? Op1 : Op0;

    int lane = threadIdx.x & 63;
    int w    = threadIdx.x >> 6;          // 8 waves
    int lrow = lane & 15, quad = lane >> 4;
    int qt = w & 3, kt = w >> 2;          // S-phase: q-tile, key-tile-of-2

    // Q fragments: this wave's 16 q-rows x full K=512 (64 VGPR)
    bf16x8 qf[16];
    const bf16_t* qp = Qb + (size_t)(q0 + qt * 16 + lrow) * C512 + quad * 8;
    #pragma unroll
    for (int ks = 0; ks < 16; ks++) qf[ks] = ld8(qp + ks * 32);

    // staging: 64 chunks (32 K + 32 V) x 512 elems; wave w stages [8w, 8w+8)
    auto stage = [&](int buf, int t) {
        #pragma unroll
        for (int ii = 0; ii < 8; ii++) {
            int cc = w * 8 + ii;
            if (cc < 32) {                        // K chunk (ks,kt)
                int ks = cc >> 1, ktc = cc & 1;
                const bf16_t* gp = Kb +
                    (size_t)(key0 + t * 32 + ktc * 16 + lrow) * C512 + ks * 32 + quad * 8;
                gload16(gp, &Kl[buf][cc * 512]);
            } else {                              // V chunk (c-tile)
                int ct = cc - 32;
                const bf16_t* gp = Vb +
                    (size_t)(ct * 16 + lrow) * SEQ + key0 + t * 32 + quad * 8;
                gload16(gp, &Vl[buf][ct * 512]);
            }
        }
    };

    f32x4 oacc[4][4] = {};                // rows m*16+quad*4+i, cols w*64+n*16+lrow
    float rs[4] = {0.f, 0.f, 0.f, 0.f};

    stage(0, 0);

    for (int t = 0; t < 64; t++) {
        int cur = t & 1;
        __syncthreads();                  // stage(t) landed; dbuf + Pl WAR
        if (t < 63) stage(1 - cur, t + 1);

        // ---- S: sa = Q[qt-tile] . K[kt-tile]^T over K=512, 2 chains ----
        f32x4 sa0 = {}, sa1 = {};
        __builtin_amdgcn_s_setprio(1);
        #pragma unroll
        for (int ks = 0; ks < 8; ks++) {
            bf16x8 kf0 = ld8(&Kl[cur][((2 * ks) * 2 + kt) * 512 + lane * 8]);
            bf16x8 kf1 = ld8(&Kl[cur][((2 * ks + 1) * 2 + kt) * 512 + lane * 8]);
            sa0 = mfma16(qf[2 * ks],     kf0, sa0);
            sa1 = mfma16(qf[2 * ks + 1], kf1, sa1);
        }
        __builtin_amdgcn_s_setprio(0);
        f32x4 sa = sa0 + sa1;
        // ---- exp -> P (LDS, A-frag-major), accumulate row-sum partials ----
        #pragma unroll
        for (int i = 0; i < 4; i++) {
            float p = __expf(fminf(sa[i], 20.0f));
            rs[i] += p;
            // P[row=quad*4+i][key=kt*16+lrow] of chunk qt, lane-linear layout
            int off = qt * 512 + (quad * 4 + i) * 8 +
                      (kt * 2 + (lrow >> 3)) * 128 + (lrow & 7);
            Pl[off] = (bf16_t)p;
        }
        asm volatile("s_waitcnt lgkmcnt(0)" ::: "memory");
        __builtin_amdgcn_s_barrier();     // P visible; staging stays in flight
        __builtin_amdgcn_sched_barrier(0);

        // ---- PV: oacc[m][n] += P[m-tile] . V[(w*4+n)-tile]^T (s-chunk=32) --
        bf16x8 pa[4];
        #pragma unroll
        for (int m = 0; m < 4; m++) pa[m] = ld8(&Pl[m * 512 + lane * 8]);
        __builtin_amdgcn_s_setprio(1);
        #pragma unroll
        for (int n = 0; n < 4; n++) {
            bf16x8 vf = ld8(&Vl[cur][(w * 4 + n) * 512 + lane * 8]);
            #pragma unroll
            for (int m = 0; m < 4; m++)
                oacc[m][n] = mfma16(pa[m], vf, oacc[m][n]);
        }
        __builtin_amdgcn_s_setprio(0);
    }

    // ---- row-sums: reduce over 16 col-lanes, one atomicAdd per row ----
    #pragma unroll
    for (int i = 0; i < 4; i++) {
        float r = rs[i];
        r += __shfl_xor(r, 1);
        r += __shfl_xor(r, 2);
        r += __shfl_xor(r, 4);
        r += __shfl_xor(r, 8);
        if (lrow == 0)
            atomicAdd(&lsum[(size_t)b * SEQ + q0 + qt * 16 + quad * 4 + i], r);
    }

    // ---- write unnormalized partial O (64 x 512 per block) ----
    #pragma unroll
    for (int m = 0; m < 4; m++) {
        int row = q0 + m * 16 + quad * 4;
        #pragma unroll
        for (int n = 0; n < 4; n++) {
            int col = w * 64 + n * 16 + lrow;
            #pragma unroll
            for (int i = 0; i < 4; i++)
                Op[((size_t)b * SEQ + row + i) * C512 + col] = (bf16_t)oacc[m][n][i];
        }
    }
}

// ---------------------------------------------------------------------------
extern "C" void kernel_launch(void* const* d_in, const int* in_sizes, int n_in,
                              void* d_out, int out_size, void* d_ws, size_t ws_size,
                              hipStream_t stream) {
    const float* x     = (const float*)d_in[0];
    const float* gamma = (const float*)d_in[1];
    const float* beta  = (const float*)d_in[2];
    const float* wq = (const float*)d_in[3];  const float* bq = (const float*)d_in[4];
    const float* wk = (const float*)d_in[5];  const float* bk = (const float*)d_in[6];
    const float* wv = (const float*)d_in[7];  const float* bv = (const float*)d_in[8];
    const float* wp = (const float*)d_in[9];  const float* bp = (const float*)d_in[10];
    float* out = (float*)d_out;

    char* ws = (char*)d_ws;
    size_t off = 0;
    float*  bqkv   = (float*)(ws + off);   off += 1536 * sizeof(float);
    float*  lsum   = (float*)(ws + off);   off += (size_t)NPIX * sizeof(float);
    float*  accum  = (float*)(ws + off);   off += 128 * sizeof(float);
    bf16_t* xn     = (bf16_t*)(ws + off);  off += (size_t)NPIX * C512 * 2;
    bf16_t* wqkvT  = (bf16_t*)(ws + off);  off += (size_t)3 * C512 * C512 * 2;
    bf16_t* wpT    = (bf16_t*)(ws + off);  off += (size_t)C512 * C512 * 2;
    bf16_t* Qb     = (bf16_t*)(ws + off);  off += (size_t)NPIX * C512 * 2;
    bf16_t* Kb     = (bf16_t*)(ws + off);  off += (size_t)NPIX * C512 * 2;
    bf16_t* VTb    = (bf16_t*)(ws + off);  off += (size_t)NPIX * C512 * 2;
    bf16_t* Op0    = (bf16_t*)(ws + off);  off += (size_t)NPIX * C512 * 2;
    bf16_t* Op1    = (bf16_t*)(ws + off);  off += (size_t)NPIX * C512 * 2;

    // zero lsum + accum (contiguous)
    hipMemsetAsync(lsum, 0, (size_t)(NPIX + 128) * sizeof(float), stream);

    gn_sum_k<<<512, 256, 0, stream>>>(x, accum);
    wt_conv_k<<<dim3(1024, 5), 256, 0, stream>>>(wq, wk, wv, wp, bq, bk, bv,
                                                 wqkvT, wpT, bqkv);
    xn_k<<<4096, 256, 0, stream>>>(x, accum, gamma, beta, xn);

    // QKV: (8192 x 1536) = xn @ wqkvT^T
    gemm128_k<0><<<dim3(64, 12, 1), 256, 0, stream>>>(
        xn, wqkvT, bqkv, nullptr, Qb, Kb, VTb, nullptr, nullptr);

    // fused attention: per-(batch, kv-half) unnormalized O partials + lsum
    fattn_k<<<256, 512, 0, stream>>>(Qb, Kb, VTb, Op0, Op1, lsum);

    // OUT: (8192 x 512) = ((Op0+Op1)/lsum) @ wpT^T + bp + x, dual-A split-K
    gemm128_k<3><<<dim3(128, 4, 1), 256, 0, stream>>>(
        Op0, wpT, bp, x, out, Op1, nullptr, nullptr, lsum);
}

// Round 7
// 302.154 us; speedup vs baseline: 1.1290x; 1.0079x over previous
//
#include <hip/hip_runtime.h>

// ---------------------------------------------------------------------------
// AttentionBlock: GroupNorm(32) -> q,k,v = xn@W+b -> softmax(q k^T / sqrt(C)) v
//                 -> out@wp+bp + x.   B=2, H=W=64, C=512, S=4096 per batch.
// Round 18: r12-exact fattn + coalesced VT epilogue (LDS bounce) in QKV.
//   r17 post-mortem: setprio+chain-split on the lockstep r12 structure cost
//   +5us (matches m190: setprio hurts barrier-synced lockstep); fusion of
//   combine2/bias into OUT/wt_conv kept (-6us). So fattn here is BYTE-EXACT
//   r12 (156.4us proven). New lever: QKV's VT epilogue was a 2-byte scatter
//   (per-lane c varies -> 64 lines/wave-store, ~32x write amplification on
//   8MB = ~15-30us hidden in the QKV dispatch). VT blocks (bn>=1024, uniform
//   per block) now bounce the 128x128 C-tile through padded LDS [128][136]
//   and store VT coalesced (8x16B contiguous per thread).
// Keeps r9/r11 gn/xn/QKV-core and r17's fused OUT (dual-A + lsum epilogue).
// ---------------------------------------------------------------------------

typedef __bf16 bf16_t;
typedef __bf16 bf16x8 __attribute__((ext_vector_type(8)));
typedef __bf16 bf16x4 __attribute__((ext_vector_type(4)));
typedef float  f32x4  __attribute__((ext_vector_type(4)));

__device__ __forceinline__ bf16x8 ld8(const bf16_t* p) {
    return *reinterpret_cast<const bf16x8*>(p);
}
__device__ __forceinline__ f32x4 mfma16(bf16x8 a, bf16x8 b, f32x4 c) {
    return __builtin_amdgcn_mfma_f32_16x16x32_bf16(a, b, c, 0, 0, 0);
}
__device__ __forceinline__ void gload16(const bf16_t* gp, bf16_t* lp) {
    // HW semantics: LDS dest = wave-uniform base + laneid*16B; gp per-lane.
    __builtin_amdgcn_global_load_lds(
        (const __attribute__((address_space(1))) void*)gp,
        (__attribute__((address_space(3))) void*)lp, 16, 0, 0);
}

#define NPIX 8192      // B*H*W
#define C512 512
#define SEQ  4096      // H*W per batch
#define QSCALE 0.044194173824159216f   // 512^-0.5

// ---------------- GroupNorm partial sums: 512 blocks (8 slices x 64 bg) -----
__global__ __launch_bounds__(256) void gn_sum_k(const float* __restrict__ x,
                                                float* __restrict__ accum) {
    int bg    = blockIdx.x >> 3;        // 0..63 = b*32+g
    int slice = blockIdx.x & 7;         // 512-pixel slice
    int b = bg >> 5, g = bg & 31;
    const float* xp = x + (size_t)b * SEQ * C512 + g * 16;
    float s = 0.f, s2 = 0.f;
    #pragma unroll
    for (int pp = 0; pp < 2; pp++) {
        int p = slice * 512 + pp * 256 + threadIdx.x;
        const float4* q = reinterpret_cast<const float4*>(xp + (size_t)p * C512);
        #pragma unroll
        for (int i = 0; i < 4; i++) {
            float4 v = q[i];
            s  += v.x + v.y + v.z + v.w;
            s2 += v.x*v.x + v.y*v.y + v.z*v.z + v.w*v.w;
        }
    }
    #pragma unroll
    for (int off = 32; off >= 1; off >>= 1) {
        s  += __shfl_down(s, off);
        s2 += __shfl_down(s2, off);
    }
    __shared__ float rs[4], rs2[4];
    int wave = threadIdx.x >> 6;
    if ((threadIdx.x & 63) == 0) { rs[wave] = s; rs2[wave] = s2; }
    __syncthreads();
    if (threadIdx.x == 0) {
        float S = rs[0] + rs[1] + rs[2] + rs[3];
        float S2 = rs2[0] + rs2[1] + rs2[2] + rs2[3];
        atomicAdd(&accum[bg * 2],     S);
        atomicAdd(&accum[bg * 2 + 1], S2);
    }
}

// ---------------- weights fp32 (k,n) -> bf16 (n,k); y==4: merged qkv bias ---
__global__ __launch_bounds__(256) void wt_conv_k(const float* wq, const float* wk,
                                                 const float* wv, const float* wp,
                                                 const float* bq, const float* bk,
                                                 const float* bv,
                                                 bf16_t* wqkvT, bf16_t* wpT,
                                                 float* bqkv) {
    int y = blockIdx.y;
    if (y == 4) {                         // merged qkv bias (Q pre-scaled)
        if (blockIdx.x >= 6) return;
        int i = blockIdx.x * 256 + threadIdx.x;       // 1536
        float v = (i < 512) ? bq[i] * QSCALE : (i < 1024) ? bk[i - 512] : bv[i - 1024];
        bqkv[i] = v;
        return;
    }
    const float* w = (y == 0) ? wq : (y == 1) ? wk : (y == 2) ? wv : wp;
    float scale = (y == 0) ? QSCALE : 1.0f;
    int tid = blockIdx.x * 256 + threadIdx.x;     // 262144 total
    int n = tid >> 9, k = tid & 511;
    bf16_t val = (bf16_t)(w[(size_t)k * C512 + n] * scale);
    if (y < 3) wqkvT[((size_t)y * C512 + n) * C512 + k] = val;
    else       wpT[(size_t)n * C512 + k] = val;
}

// ---------------- xn = groupnorm(x)*gamma+beta -> bf16 ----------------------
__global__ __launch_bounds__(256) void xn_k(const float* __restrict__ x,
                                            const float* __restrict__ accum,
                                            const float* __restrict__ gamma,
                                            const float* __restrict__ beta,
                                            bf16_t* __restrict__ xn) {
    size_t idx = ((size_t)blockIdx.x * 256 + threadIdx.x) * 4;   // elem index
    int c = (int)(idx & 511);
    size_t pix = idx >> 9;
    int b = (int)(pix >> 12);
    int g = c >> 4;
    float sum = accum[(b * 32 + g) * 2];
    float ssq = accum[(b * 32 + g) * 2 + 1];
    float mean = sum * (1.f / 65536.f);
    float var  = ssq * (1.f / 65536.f) - mean * mean;
    float rstd = rsqrtf(var + 1e-5f);
    float4 v  = *reinterpret_cast<const float4*>(x + idx);
    float4 gm = *reinterpret_cast<const float4*>(gamma + c);
    float4 bt = *reinterpret_cast<const float4*>(beta + c);
    bf16x4 o;
    o[0] = (bf16_t)((v.x - mean) * rstd * gm.x + bt.x);
    o[1] = (bf16_t)((v.y - mean) * rstd * gm.y + bt.y);
    o[2] = (bf16_t)((v.z - mean) * rstd * gm.z + bt.z);
    o[3] = (bf16_t)((v.w - mean) * rstd * gm.w + bt.w);
    *reinterpret_cast<bf16x4*>(xn + idx) = o;
}

// ---------------- unified TMx128-tile GEMM (m97 structure) ------------------
// MODE 0: QKV (TM=128) — A=xn, B=wqkvT(1536x512). Epilogue: +bqkv; blocks
//                y=0-3 -> Q, y=4-7 -> K (row-major direct); y=8-11 -> VT via
//                LDS-bounce transpose, coalesced 16B stores.
// MODE 3: OUT (TM=64)  — dual-A split-K: ksteps 0-15 over Op0, 16-31 over
//                Op1 (out1), same accumulator. Epilogue: acc/lsum[row]
//                + bp + resid, fp32 out.
template <int MODE>
__global__ __launch_bounds__(256, 2) void gemm128_k(
        const bf16_t* __restrict__ Aall, const bf16_t* __restrict__ Ball,
        const float* __restrict__ bias, const float* __restrict__ resid,
        void* __restrict__ out0, void* __restrict__ out1,
        void* __restrict__ out2, void* __restrict__ out3,
        float* __restrict__ lsum) {
    constexpr int TM  = (MODE == 3) ? 64 : 128;
    constexpr int ASZ = TM * 32;          // A elems per buffer
    constexpr int ACH = TM / 16;          // A chunks per step
    constexpr int CPW = (ACH + 8) / 4;    // staging chunks per wave
    constexpr int MI  = TM / 32;          // m-tiles per wave
    constexpr int SME = (MODE == 0) ? (128 * 136) : (2 * ASZ + 8192);
    __shared__ bf16_t smem[SME];          // A dbuf + B dbuf (+ VT bounce tile)

    int lane = threadIdx.x & 63;
    int w    = threadIdx.x >> 6;          // 4 waves, 2x2
    int wr   = w >> 1, wc = w & 1;
    int lrow = lane & 15, quad = lane >> 4;

    const bf16_t* A  = Aall;
    const bf16_t* A1 = (MODE == 3) ? (const bf16_t*)out1 : nullptr;
    const bf16_t* B  = Ball;
    size_t lda = 512, ldb = 512;
    int ksteps = (MODE == 3) ? 32 : 16;

    int bm = blockIdx.x * TM, bn = blockIdx.y * 128;

    // stage K-step ks into buffer buf: ACH A-chunks + 8 B-chunks
    auto stage = [&](int buf, int ks) {
        const bf16_t* Ap = (MODE == 3 && ks >= 16) ? A1 : A;
        size_t k0 = (size_t)(MODE == 3 ? (ks & 15) : ks) * 32;
        #pragma unroll
        for (int ii = 0; ii < CPW; ii++) {
            int c = w * CPW + ii;
            if (c < ACH) {
                const bf16_t* gpA = Ap + (size_t)(bm + c * 16 + lrow) * lda + k0 + quad * 8;
                gload16(gpA, &smem[buf * ASZ + c * 512]);
            } else {
                int cb = c - ACH;
                const bf16_t* gpB = B + (size_t)(bn + cb * 16 + lrow) * ldb + k0 + quad * 8;
                gload16(gpB, &smem[2 * ASZ + buf * 4096 + cb * 512]);
            }
        }
    };

    f32x4 acc[MI][4] = {};

    stage(0, 0);

    for (int ks = 0; ks < ksteps; ks++) {
        int cur = ks & 1;
        __syncthreads();                 // drains stage(ks); WAR for dbuf
        if (ks + 1 < ksteps) stage(1 - cur, ks + 1);

        const bf16_t* al = &smem[cur * ASZ + (wr * MI) * 512];
        const bf16_t* bl = &smem[2 * ASZ + cur * 4096 + (wc * 4) * 512];
        bf16x8 af[MI], bf[4];
        #pragma unroll
        for (int m = 0; m < MI; m++) af[m] = ld8(al + m * 512 + lane * 8);
        #pragma unroll
        for (int n = 0; n < 4; n++) bf[n] = ld8(bl + n * 512 + lane * 8);
        #pragma unroll
        for (int m = 0; m < MI; m++)
            #pragma unroll
            for (int n = 0; n < 4; n++)
                acc[m][n] = mfma16(af[m], bf[n], acc[m][n]);
    }

    // ---- epilogue; C/D layout: col=lane&15, row=quad*4+reg ----
    if (MODE == 0 && bn >= 1024) {
        // VT blocks: bounce C-tile through LDS, store transposed + coalesced.
        __syncthreads();                  // all waves done with smem (k-loop)
        #pragma unroll
        for (int m = 0; m < MI; m++) {
            int lr0 = wr * 64 + m * 16 + quad * 4;
            #pragma unroll
            for (int n = 0; n < 4; n++) {
                int lc = wc * 64 + n * 16 + lrow;
                float bsc = bias[bn + lc];
                #pragma unroll
                for (int i = 0; i < 4; i++)
                    smem[(lr0 + i) * 136 + lc] = (bf16_t)(acc[m][n][i] + bsc);
            }
        }
        __syncthreads();
        // thread t: VT row c = bn-1024+cc, s-range bm + sh*64 .. +63
        int cc = threadIdx.x >> 1, sh = threadIdx.x & 1;
        int b = bm >> 12, s0 = (bm & 4095) + sh * 64;
        bf16_t* VTp = (bf16_t*)out2 +
                      ((size_t)(b * C512 + (bn - 1024) + cc)) * SEQ + s0;
        #pragma unroll
        for (int j = 0; j < 8; j++) {
            bf16x8 v;
            #pragma unroll
            for (int e = 0; e < 8; e++)
                v[e] = smem[(sh * 64 + j * 8 + e) * 136 + cc];
            *reinterpret_cast<bf16x8*>(VTp + j * 8) = v;
        }
        return;
    }
    #pragma unroll
    for (int m = 0; m < MI; m++) {
        int rowb = bm + wr * (TM / 2) + m * 16 + quad * 4;
        #pragma unroll
        for (int n = 0; n < 4; n++) {
            int col = bn + wc * 64 + n * 16 + lrow;
            #pragma unroll
            for (int i = 0; i < 4; i++) {
                int row = rowb + i;
                float v = acc[m][n][i];
                if (MODE == 0) {
                    int seg = col >> 9, c = col & 511;
                    bf16_t val = (bf16_t)(v + bias[col]);
                    if (seg == 0) ((bf16_t*)out0)[(size_t)row * C512 + c] = val;
                    else          ((bf16_t*)out1)[(size_t)row * C512 + c] = val;
                } else {
                    size_t idx = (size_t)row * C512 + col;
                    float inv = 1.0f / lsum[row];
                    ((float*)out0)[idx] = v * inv + bias[col] + resid[idx];
                }
            }
        }
    }
}

// ---------------- fused attention: O_partial = exp(Q K^T) V, lsum ----------
// BYTE-EXACT r12 champion (156.4us): 256 blocks x 512 thr (8 waves).
// Block = (batch, kv-half of 2048 keys, 64 q-rows), XCD-swizzled so each XCD
// streams one (b,kv) K/V-half (4MB=L2). Per 32-key chunk: S = Q.K^T
// (16 MFMA/wave, Q-frags in regs), P=exp(min(s,20)) through a 4KB LDS
// buffer, O += P.V (16 MFMA/wave). K/VT staged frag-major via
// global_load_lds, double-buffered; mid-chunk barrier is raw s_barrier +
// lgkmcnt(0) so staging stays in flight across it.
__global__ __launch_bounds__(512, 1) void fattn_k(
        const bf16_t* __restrict__ Q, const bf16_t* __restrict__ K,
        const bf16_t* __restrict__ VT, bf16_t* __restrict__ Op0,
        bf16_t* __restrict__ Op1, float* __restrict__ lsum) {
    __shared__ bf16_t Kl[2][32 * 512];   // [buf][32 keys x 512 k] frag-major
    __shared__ bf16_t Vl[2][512 * 32];   // [buf][512 c x 32 s]  frag-major
    __shared__ bf16_t Pl[64 * 32];       // P chunk, A-frag-major (4 chunks)

    int bid = blockIdx.x;
    int xcd = bid & 7, loc = bid >> 3;    // 8 XCDs x 32 blocks
    int b   = (xcd >> 1) & 1;
    int kv  = xcd & 1;
    int q0  = ((xcd >> 2) * 32 + loc) * 64;
    int key0 = kv * 2048;

    const bf16_t* Qb = Q  + (size_t)b * SEQ * C512;
    const bf16_t* Kb = K  + (size_t)b * SEQ * C512;
    const bf16_t* Vb = VT + (size_t)b * C512 * SEQ;
    bf16_t* Op = kv ? Op1 : Op0;

    int lane = threadIdx.x & 63;
    int w    = threadIdx.x >> 6;          // 8 waves
    int lrow = lane & 15, quad = lane >> 4;
    int qt = w & 3, kt = w >> 2;          // S-phase: q-tile, key-tile-of-2

    // Q fragments: this wave's 16 q-rows x full K=512 (64 VGPR)
    bf16x8 qf[16];
    const bf16_t* qp = Qb + (size_t)(q0 + qt * 16 + lrow) * C512 + quad * 8;
    #pragma unroll
    for (int ks = 0; ks < 16; ks++) qf[ks] = ld8(qp + ks * 32);

    // staging: 64 chunks (32 K + 32 V) x 512 elems; wave w stages [8w, 8w+8)
    auto stage = [&](int buf, int t) {
        #pragma unroll
        for (int ii = 0; ii < 8; ii++) {
            int cc = w * 8 + ii;
            if (cc < 32) {                        // K chunk (ks,kt)
                int ks = cc >> 1, ktc = cc & 1;
                const bf16_t* gp = Kb +
                    (size_t)(key0 + t * 32 + ktc * 16 + lrow) * C512 + ks * 32 + quad * 8;
                gload16(gp, &Kl[buf][cc * 512]);
            } else {                              // V chunk (c-tile)
                int ct = cc - 32;
                const bf16_t* gp = Vb +
                    (size_t)(ct * 16 + lrow) * SEQ + key0 + t * 32 + quad * 8;
                gload16(gp, &Vl[buf][ct * 512]);
            }
        }
    };

    f32x4 oacc[4][4] = {};                // rows m*16+quad*4+i, cols w*64+n*16+lrow
    float rs[4] = {0.f, 0.f, 0.f, 0.f};

    stage(0, 0);

    for (int t = 0; t < 64; t++) {
        int cur = t & 1;
        __syncthreads();                  // stage(t) landed; dbuf + Pl WAR
        if (t < 63) stage(1 - cur, t + 1);

        // ---- S: sa = Q[qt-tile] . K[kt-tile]^T over K=512 ----
        f32x4 sa = {0.f, 0.f, 0.f, 0.f};
        #pragma unroll
        for (int ks = 0; ks < 16; ks++) {
            bf16x8 bf = ld8(&Kl[cur][(ks * 2 + kt) * 512 + lane * 8]);
            sa = mfma16(qf[ks], bf, sa);
        }
        // ---- exp -> P (LDS, A-frag-major), accumulate row-sum partials ----
        #pragma unroll
        for (int i = 0; i < 4; i++) {
            float p = __expf(fminf(sa[i], 20.0f));
            rs[i] += p;
            // P[row=quad*4+i][key=kt*16+lrow] of chunk qt, lane-linear layout
            int off = qt * 512 + (quad * 4 + i) * 8 +
                      (kt * 2 + (lrow >> 3)) * 128 + (lrow & 7);
            Pl[off] = (bf16_t)p;
        }
        asm volatile("s_waitcnt lgkmcnt(0)" ::: "memory");
        __builtin_amdgcn_s_barrier();     // P visible; staging stays in flight
        __builtin_amdgcn_sched_barrier(0);

        // ---- PV: oacc[m][n] += P[m-tile] . V[(w*4+n)-tile]^T (s-chunk=32) --
        bf16x8 pa[4];
        #pragma unroll
        for (int m = 0; m < 4; m++) pa[m] = ld8(&Pl[m * 512 + lane * 8]);
        #pragma unroll
        for (int n = 0; n < 4; n++) {
            bf16x8 vf = ld8(&Vl[cur][(w * 4 + n) * 512 + lane * 8]);
            #pragma unroll
            for (int m = 0; m < 4; m++)
                oacc[m][n] = mfma16(pa[m], vf, oacc[m][n]);
        }
    }

    // ---- row-sums: reduce over 16 col-lanes, one atomicAdd per row ----
    #pragma unroll
    for (int i = 0; i < 4; i++) {
        float r = rs[i];
        r += __shfl_xor(r, 1);
        r += __shfl_xor(r, 2);
        r += __shfl_xor(r, 4);
        r += __shfl_xor(r, 8);
        if (lrow == 0)
            atomicAdd(&lsum[(size_t)b * SEQ + q0 + qt * 16 + quad * 4 + i], r);
    }

    // ---- write unnormalized partial O (64 x 512 per block) ----
    #pragma unroll
    for (int m = 0; m < 4; m++) {
        int row = q0 + m * 16 + quad * 4;
        #pragma unroll
        for (int n = 0; n < 4; n++) {
            int col = w * 64 + n * 16 + lrow;
            #pragma unroll
            for (int i = 0; i < 4; i++)
                Op[((size_t)b * SEQ + row + i) * C512 + col] = (bf16_t)oacc[m][n][i];
        }
    }
}

// ---------------------------------------------------------------------------
extern "C" void kernel_launch(void* const* d_in, const int* in_sizes, int n_in,
                              void* d_out, int out_size, void* d_ws, size_t ws_size,
                              hipStream_t stream) {
    const float* x     = (const float*)d_in[0];
    const float* gamma = (const float*)d_in[1];
    const float* beta  = (const float*)d_in[2];
    const float* wq = (const float*)d_in[3];  const float* bq = (const float*)d_in[4];
    const float* wk = (const float*)d_in[5];  const float* bk = (const float*)d_in[6];
    const float* wv = (const float*)d_in[7];  const float* bv = (const float*)d_in[8];
    const float* wp = (const float*)d_in[9];  const float* bp = (const float*)d_in[10];
    float* out = (float*)d_out;

    char* ws = (char*)d_ws;
    size_t off = 0;
    float*  bqkv   = (float*)(ws + off);   off += 1536 * sizeof(float);
    float*  lsum   = (float*)(ws + off);   off += (size_t)NPIX * sizeof(float);
    float*  accum  = (float*)(ws + off);   off += 128 * sizeof(float);
    bf16_t* xn     = (bf16_t*)(ws + off);  off += (size_t)NPIX * C512 * 2;
    bf16_t* wqkvT  = (bf16_t*)(ws + off);  off += (size_t)3 * C512 * C512 * 2;
    bf16_t* wpT    = (bf16_t*)(ws + off);  off += (size_t)C512 * C512 * 2;
    bf16_t* Qb     = (bf16_t*)(ws + off);  off += (size_t)NPIX * C512 * 2;
    bf16_t* Kb     = (bf16_t*)(ws + off);  off += (size_t)NPIX * C512 * 2;
    bf16_t* VTb    = (bf16_t*)(ws + off);  off += (size_t)NPIX * C512 * 2;
    bf16_t* Op0    = (bf16_t*)(ws + off);  off += (size_t)NPIX * C512 * 2;
    bf16_t* Op1    = (bf16_t*)(ws + off);  off += (size_t)NPIX * C512 * 2;

    // zero lsum + accum (contiguous)
    hipMemsetAsync(lsum, 0, (size_t)(NPIX + 128) * sizeof(float), stream);

    gn_sum_k<<<512, 256, 0, stream>>>(x, accum);
    wt_conv_k<<<dim3(1024, 5), 256, 0, stream>>>(wq, wk, wv, wp, bq, bk, bv,
                                                 wqkvT, wpT, bqkv);
    xn_k<<<4096, 256, 0, stream>>>(x, accum, gamma, beta, xn);

    // QKV: (8192 x 1536) = xn @ wqkvT^T
    gemm128_k<0><<<dim3(64, 12, 1), 256, 0, stream>>>(
        xn, wqkvT, bqkv, nullptr, Qb, Kb, VTb, nullptr, nullptr);

    // fused attention: per-(batch, kv-half) unnormalized O partials + lsum
    fattn_k<<<256, 512, 0, stream>>>(Qb, Kb, VTb, Op0, Op1, lsum);

    // OUT: (8192 x 512) = ((Op0+Op1)/lsum) @ wpT^T + bp + x, dual-A split-K
    gemm128_k<3><<<dim3(128, 4, 1), 256, 0, stream>>>(
        Op0, wpT, bp, x, out, Op1, nullptr, nullptr, lsum);
}